// Round 6
// baseline (313.442 us; speedup 1.0000x reference)
//
#include <hip/hip_runtime.h>
#include <stdint.h>

typedef __attribute__((ext_vector_type(8))) short short8;
typedef __attribute__((ext_vector_type(4))) float f32x4;

#define T_STEPS 256
#define BATCH   128

// LDS-visibility barrier that does NOT drain vmcnt (global prefetch stays in flight)
#define LDS_BARRIER() asm volatile("s_waitcnt lgkmcnt(0)\n\ts_barrier" ::: "memory")

static __device__ inline unsigned short f2bf(float f) {   // RNE fp32->bf16 (W2 hi/lo path)
    unsigned int u = __float_as_uint(f);
    unsigned int r = u + 0x7FFFu + ((u >> 16) & 1u);
    return (unsigned short)(r >> 16);
}
static __device__ inline unsigned pack_hi16(unsigned a, unsigned b) {
    return (a >> 16) | (b & 0xFFFF0000u);
}

// ---- k_prep: blocks 0..255 -> W2 hi/lo split; 256..257 -> W1 3-split rows (scaled 1/thr1);
//      blocks 258..769 -> X B-fragments (normalized, exact 3-way bf16 trunc split)
// W1rows[h][64]: [0..15]=Wh, [16..31]=Wm, [32..47]=Wl, [48..63]=0  (W' = W1 / thr1[h])
// Xf[t][btile][frag3][lane64]: B1=[xh|xh], B2=[xm|xm], B3=[xl|xh]
__global__ __launch_bounds__(256) void k_prep(
    const float* __restrict__ W2, const float* __restrict__ W1,
    const float* __restrict__ b1, const float* __restrict__ thr1,
    const float* __restrict__ imin_p, const float* __restrict__ imax_p,
    const float* __restrict__ batch,
    unsigned short* __restrict__ W2hi, unsigned short* __restrict__ W2lo,
    unsigned short* __restrict__ W1rows, float* __restrict__ b1s,
    unsigned short* __restrict__ Xf)
{
    int blk = blockIdx.x, tid = threadIdx.x;
    if (blk < 256) {
        int gid = blk * 256 + tid;          // 65536 threads, 4 elems each
        f32x4 wv = *(const f32x4*)(W2 + (size_t)gid * 4);
        unsigned short hi[4], lo[4];
#pragma unroll
        for (int e = 0; e < 4; ++e) {
            float wf = wv[e];
            unsigned short h = f2bf(wf);
            float hf = __uint_as_float(((unsigned int)h) << 16);
            hi[e] = h;
            lo[e] = f2bf(wf - hf);
        }
        uint2 ph, pl;
        ph.x = (unsigned)hi[0] | ((unsigned)hi[1] << 16);
        ph.y = (unsigned)hi[2] | ((unsigned)hi[3] << 16);
        pl.x = (unsigned)lo[0] | ((unsigned)lo[1] << 16);
        pl.y = (unsigned)lo[2] | ((unsigned)lo[3] << 16);
        *(uint2*)(W2hi + (size_t)gid * 4) = ph;
        *(uint2*)(W2lo + (size_t)gid * 4) = pl;
    } else if (blk < 258) {
        int h = (blk - 256) * 256 + tid;    // 512 rows
        float wsc = 1.0f / thr1[h];
        unsigned short row[64];
#pragma unroll
        for (int k = 0; k < 16; ++k) {
            float wv = W1[h * 16 + k] * wsc;
            unsigned a = __float_as_uint(wv) & 0xFFFF0000u;
            float r1 = wv - __uint_as_float(a);
            unsigned m = __float_as_uint(r1) & 0xFFFF0000u;
            float r2 = r1 - __uint_as_float(m);
            unsigned l = __float_as_uint(r2) & 0xFFFF0000u;
            row[k]      = (unsigned short)(a >> 16);
            row[16 + k] = (unsigned short)(m >> 16);
            row[32 + k] = (unsigned short)(l >> 16);
            row[48 + k] = 0;
        }
        b1s[h] = b1[h] * wsc;
        uint4* dst = (uint4*)(W1rows + (size_t)h * 64);
#pragma unroll
        for (int i = 0; i < 8; ++i) dst[i] = ((uint4*)row)[i];
    } else {
        int gid   = (blk - 258) * 256 + tid;   // 131072 = 256t * 8btile * 64lane
        int lane  = gid & 63;
        int btile = (gid >> 6) & 7;
        int t     = gid >> 9;
        int q     = lane >> 4, m15 = lane & 15;
        int b     = btile * 16 + m15;
        float imin = imin_p[0];
        float isc  = 1.0f / (imax_p[0] - imin);
        const float* xp = batch + ((size_t)b * T_STEPS + t) * 16 + (q & 1) * 8;
        unsigned uh[8], um[8], ul[8];
#pragma unroll
        for (int j = 0; j < 8; ++j) {
            float xv = (xp[j] - imin) * isc;
            unsigned a = __float_as_uint(xv) & 0xFFFF0000u;
            float r1 = xv - __uint_as_float(a);
            unsigned m = __float_as_uint(r1) & 0xFFFF0000u;
            float r2 = r1 - __uint_as_float(m);
            unsigned l = __float_as_uint(r2) & 0xFFFF0000u;
            uh[j] = a; um[j] = m; ul[j] = l;
        }
        uint4 B1, B2, XL;
        B1.x = pack_hi16(uh[0], uh[1]); B1.y = pack_hi16(uh[2], uh[3]);
        B1.z = pack_hi16(uh[4], uh[5]); B1.w = pack_hi16(uh[6], uh[7]);
        B2.x = pack_hi16(um[0], um[1]); B2.y = pack_hi16(um[2], um[3]);
        B2.z = pack_hi16(um[4], um[5]); B2.w = pack_hi16(um[6], um[7]);
        XL.x = pack_hi16(ul[0], ul[1]); XL.y = pack_hi16(ul[2], ul[3]);
        XL.z = pack_hi16(ul[4], ul[5]); XL.w = pack_hi16(ul[6], ul[7]);
        uint4 B3 = (q < 2) ? XL : B1;   // [xl|xh]
        unsigned short* dst = Xf + (((size_t)t * 8 + btile) * 3) * 512 + lane * 8;
        *(uint4*)(dst +    0) = B1;
        *(uint4*)(dst +  512) = B2;
        *(uint4*)(dst + 1024) = B3;
    }
}

// ---- main: 1024 threads (16 waves, 4/SIMD); 1 barrier/step; fully balanced waves
__global__ __launch_bounds__(1024, 4) void k_main(
    const unsigned short* __restrict__ Xf,
    const unsigned short* __restrict__ W2hi, const unsigned short* __restrict__ W2lo,
    const unsigned short* __restrict__ W1rows, const float* __restrict__ b1s,
    const float* __restrict__ beta1, const float* __restrict__ b2,
    const float* __restrict__ beta2, const float* __restrict__ thr2,
    unsigned short* __restrict__ spkbits)
{
    __shared__ unsigned short Aw[8192];   // 16 waves x 1KB wave-private spike staging
    __shared__ float Cbuf[2][4352];       // [buf][b 16][j 16][wp 17 pad] (34 KB)

    int tid  = threadIdx.x;
    int lane = tid & 63;
    int w    = tid >> 6;                  // 0..15: GEMM1 h-chunk of 32 = GEMM2 K-chunk of 32
    int q    = lane >> 4, m15 = lane & 15;
    int btile = blockIdx.x & 7;
    int slice = blockIdx.x >> 3;

    // W1 A-frags: A1=[Wh|Wm], A2=[Wh|Wl]
    short8 A1[2], A2[2];
#pragma unroll
    for (int c = 0; c < 2; ++c) {
        const unsigned short* rp = W1rows + (size_t)(w * 32 + c * 16 + m15) * 64;
        A1[c] = *(const short8*)(rp + q * 8);
        A2[c] = *(const short8*)(rp + q * 8 + (q >> 1) * 16);
    }
    // W2 B-frags for K-window [w*32, w*32+32)
    int jg = slice * 16 + m15;
    short8 bhi = *(const short8*)(W2hi + (size_t)jg * 512 + w * 32 + q * 8);
    short8 blo = *(const short8*)(W2lo + (size_t)jg * 512 + w * 32 + q * 8);

    // LIF1 params: states (b=m15, h = w*32 + c*16 + q*4 + r)
    f32x4 b14[2], bet1[2];
#pragma unroll
    for (int c = 0; c < 2; ++c) {
        int h0 = w * 32 + c * 16 + q * 4;
        b14[c] = *(const f32x4*)(b1s + h0);
        f32x4 bb = *(const f32x4*)(beta1 + h0);
#pragma unroll
        for (int r = 0; r < 4; ++r) bet1[c][r] = fminf(fmaxf(bb[r], 0.0f), 1.0f);
    }
    float m1[8], spk1f[8];
#pragma unroll
    for (int i = 0; i < 8; ++i) { m1[i] = 0.0f; spk1f[i] = 0.0f; }

    // LIF2: wave w owns b = btile*16 + w; lane handles j = jg (replicated over lane-quads)
    float beta2r = fminf(fmaxf(beta2[jg], 0.0f), 1.0f);
    float thr2r  = thr2[jg];
    float nthr2  = -thr2r;
    float b2r    = b2[jg];
    float m2 = 0.0f, spk2f = 0.0f;

    // X frags (3 per step)
    const unsigned short* xbase = Xf + ((size_t)btile * 3) * 512 + lane * 8;
    uint4 xc[3], xn[3];
#pragma unroll
    for (int f = 0; f < 3; ++f) xc[f] = *(const uint4*)(xbase + f * 512);

    unsigned short* myAw = Aw + w * 512;
    int wr0 = (0 * 2 + (q >> 1)) * 128 + (m15 ^ (q >> 1)) * 8 + (q & 1) * 4;
    int wr1 = (1 * 2 + (q >> 1)) * 128 + (m15 ^ (q >> 1)) * 8 + (q & 1) * 4;
    int rdo = (q * 16 + (m15 ^ (q & 1))) * 8;
    int p4  = (lane >> 4) * 4;            // reduce partial-group

    auto body = [&](int ts, uint4* xcur, uint4* xnx) __attribute__((always_inline)) {
        int buf = ts & 1;
        // prefetch t+1 X frags (in flight across the barrier)
        int tn = (ts + 1 < T_STEPS) ? ts + 1 : ts;
        const unsigned short* xp = xbase + (size_t)tn * 12288;
#pragma unroll
        for (int f = 0; f < 3; ++f) xnx[f] = *(const uint4*)(xp + f * 512);

        // GEMM1: 3-term split (err ~2^-24), 6 MFMA
        union { uint4 u; short8 s; } Bf[3];
#pragma unroll
        for (int f = 0; f < 3; ++f) Bf[f].u = xcur[f];
        f32x4 D[2];
#pragma unroll
        for (int c = 0; c < 2; ++c) {
            D[c] = b14[c];
            D[c] = __builtin_amdgcn_mfma_f32_16x16x32_bf16(A1[c], Bf[0].s, D[c], 0, 0, 0);
            D[c] = __builtin_amdgcn_mfma_f32_16x16x32_bf16(A1[c], Bf[1].s, D[c], 0, 0, 0);
            D[c] = __builtin_amdgcn_mfma_f32_16x16x32_bf16(A2[c], Bf[2].s, D[c], 0, 0, 0);
        }
        // LIF1 (scaled: thr == 1)
#pragma unroll
        for (int i = 0; i < 8; ++i) {
            int c = i >> 2, r = i & 3;
            float mv = fmaf(bet1[c][r], m1[i], D[c][r]);
            mv -= spk1f[i];
            bool sp = mv > 1.0f;
            m1[i] = mv;
            spk1f[i] = sp ? 1.0f : 0.0f;
        }
        // spikes -> wave-private LDS in consumer A-frag order (XOR-swizzled)
        {
            uint2 pk0, pk1;
            pk0.x = pack_hi16(__float_as_uint(spk1f[0]), __float_as_uint(spk1f[1]));
            pk0.y = pack_hi16(__float_as_uint(spk1f[2]), __float_as_uint(spk1f[3]));
            pk1.x = pack_hi16(__float_as_uint(spk1f[4]), __float_as_uint(spk1f[5]));
            pk1.y = pack_hi16(__float_as_uint(spk1f[6]), __float_as_uint(spk1f[7]));
            *(uint2*)(myAw + wr0) = pk0;
            *(uint2*)(myAw + wr1) = pk1;
        }
        union { uint4 u; short8 s; } af;
        af.u = *(uint4*)(myAw + rdo);
        // GEMM2 partial: K=32 chunk, hi then lo chained
        f32x4 C2 = { 0.f, 0.f, 0.f, 0.f };
        C2 = __builtin_amdgcn_mfma_f32_16x16x32_bf16(af.s, bhi, C2, 0, 0, 0);
        C2 = __builtin_amdgcn_mfma_f32_16x16x32_bf16(af.s, blo, C2, 0, 0, 0);
        // scatter partials: Cbuf[b= q*4+r][j=m15][wp=w]  (b*272 + j*17 + w)
#pragma unroll
        for (int r = 0; r < 4; ++r)
            Cbuf[buf][(q * 4 + r) * 272 + m15 * 17 + w] = C2[r];
        LDS_BARRIER();
        // distributed K-reduce: wave w reduces item b=w; lanes (p=lane>>4, j=m15)
        {
            float s0, s1, s2, s3;
            int base = w * 272 + m15 * 17 + p4;
            s0 = Cbuf[buf][base + 0];
            s1 = Cbuf[buf][base + 1];
            s2 = Cbuf[buf][base + 2];
            s3 = Cbuf[buf][base + 3];
            float s = (s0 + s1) + (s2 + s3);
            s += __shfl_xor(s, 16, 64);
            s += __shfl_xor(s, 32, 64);
            // LIF2 (replicated across the 4 lane-quads; identical values)
            float cur2 = b2r + s;
            m2 = fmaf(beta2r, m2, cur2);
            m2 = fmaf(spk2f, nthr2, m2);
            bool sp2 = m2 > thr2r;
            spk2f = sp2 ? 1.0f : 0.0f;
            unsigned long long mask = __ballot(sp2);
            if (lane == 0) {
                spkbits[((size_t)ts * BATCH + btile * 16 + w) * 32 + slice] =
                    (unsigned short)(mask & 0xFFFFu);
            }
        }
    };

#pragma unroll 1
    for (int ts = 0; ts < T_STEPS; ts += 2) {
        body(ts, xc, xn);
        body(ts + 1, xn, xc);
    }
}

// ---- action bit-GEMM + beta-weighted scan over t (R3/R4-proven) ----
__global__ __launch_bounds__(256) void k_act(
    const unsigned short* __restrict__ spkbits,
    const float* __restrict__ Wa, const float* __restrict__ ba,
    const float* __restrict__ beta_act_p, float* __restrict__ out)
{
    __shared__ f32x4 waT[512];
    __shared__ f32x4 sc[256];
    int tid = threadIdx.x;   // = timestep
    int b   = blockIdx.x;

    for (int j = tid; j < 512; j += 256) {
        f32x4 v = { Wa[j], Wa[512 + j], Wa[1024 + j], Wa[1536 + j] };
        waT[j] = v;
    }
    float bact = fminf(fmaxf(beta_act_p[0], 0.0f), 1.0f);
    f32x4 acc = { ba[0], ba[1], ba[2], ba[3] };
    __syncthreads();

    const unsigned short* sp = spkbits + ((size_t)tid * BATCH + b) * 32;
    unsigned int wbuf[16];
#pragma unroll
    for (int r = 0; r < 4; ++r) {
        uint4 v = *(const uint4*)(sp + r * 8);
        wbuf[r*4+0] = v.x; wbuf[r*4+1] = v.y; wbuf[r*4+2] = v.z; wbuf[r*4+3] = v.w;
    }
    for (int s = 0; s < 32; ++s) {
        unsigned int wd = (wbuf[s >> 1] >> ((s & 1) * 16)) & 0xFFFFu;
#pragma unroll
        for (int i = 0; i < 16; ++i) {
            float sel = ((wd >> i) & 1u) ? 1.0f : 0.0f;
            f32x4 wv = waT[s * 16 + i];
            acc[0] = fmaf(sel, wv[0], acc[0]);
            acc[1] = fmaf(sel, wv[1], acc[1]);
            acc[2] = fmaf(sel, wv[2], acc[2]);
            acc[3] = fmaf(sel, wv[3], acc[3]);
        }
    }
    sc[tid] = acc;
    __syncthreads();
    float bd = bact;
    for (int d = 1; d < 256; d <<= 1) {
        f32x4 cv = sc[tid];
        f32x4 pv = { 0.f, 0.f, 0.f, 0.f };
        if (tid >= d) pv = sc[tid - d];
        __syncthreads();
        cv[0] = fmaf(bd, pv[0], cv[0]);
        cv[1] = fmaf(bd, pv[1], cv[1]);
        cv[2] = fmaf(bd, pv[2], cv[2]);
        cv[3] = fmaf(bd, pv[3], cv[3]);
        sc[tid] = cv;
        __syncthreads();
        bd *= bd;
    }
    f32x4 res = sc[tid];
    *(f32x4*)(out + (size_t)tid * 512 + b * 4) = res;
}

extern "C" void kernel_launch(void* const* d_in, const int* in_sizes, int n_in,
                              void* d_out, int out_size, void* d_ws, size_t ws_size,
                              hipStream_t stream)
{
    const float* batch    = (const float*)d_in[0];
    const float* W1       = (const float*)d_in[1];
    const float* b1       = (const float*)d_in[2];
    const float* beta1    = (const float*)d_in[3];
    const float* thr1     = (const float*)d_in[4];
    const float* W2       = (const float*)d_in[5];
    const float* b2       = (const float*)d_in[6];
    const float* beta2    = (const float*)d_in[7];
    const float* thr2     = (const float*)d_in[8];
    const float* Wa       = (const float*)d_in[9];
    const float* ba       = (const float*)d_in[10];
    const float* beta_act = (const float*)d_in[11];
    const float* inp_min  = (const float*)d_in[12];
    const float* inp_max  = (const float*)d_in[13];
    float* out            = (float*)d_out;

    char* ws = (char*)d_ws;
    unsigned short* W2hi    = (unsigned short*)ws;                          // 512 KiB
    unsigned short* W2lo    = (unsigned short*)(ws + (512u << 10));         // 512 KiB
    unsigned short* W1rows  = (unsigned short*)(ws + (1u << 20));           // 64 KiB
    float*          b1s     = (float*)(ws + (1u << 20) + (64u << 10));      // 2 KiB
    unsigned short* Xf      = (unsigned short*)(ws + (2u << 20));           // 6 MiB
    unsigned short* spkbits = (unsigned short*)(ws + (8u << 20));           // 2 MiB

    hipLaunchKernelGGL(k_prep, dim3(770), dim3(256), 0, stream,
                       W2, W1, b1, thr1, inp_min, inp_max, batch,
                       W2hi, W2lo, W1rows, b1s, Xf);
    hipLaunchKernelGGL(k_main, dim3(256), dim3(1024), 0, stream,
                       Xf, W2hi, W2lo, W1rows, b1s, beta1, b2, beta2, thr2, spkbits);
    hipLaunchKernelGGL(k_act, dim3(128), dim3(256), 0, stream, spkbits, Wa, ba, beta_act, out);
}